// Round 7
// baseline (146.000 us; speedup 1.0000x reference)
//
#include <hip/hip_runtime.h>
#include <math.h>

#define BATCH 4
#define NPTS 8192
#define TPB 512
#define RPB 128                      // rows per block
#define NBLK (NPTS / RPB)            // 64 row-blocks per (b,dir)
#define CHUNK_COLS 512               // one column per thread per chunk
#define NCHUNK (NPTS / CHUNK_COLS)   // 16

// ---------------------------------------------------------------------------
// SCALE-SPLIT packed MFMA Chamfer (2 MFMAs per 32x32 tile).
//
// Session finding: 5 failing rounds (R1-R4,R6) vs 1 passing (R5) partition
// exactly on "mixed-magnitude products inside one MFMA k-tree".  R6 proved
// the k-pairing is a clean permutation (on-chip probe, all guards passed)
// and compensated for it -- still ~4e-2 off.  Hypothesis: the bf16 MFMA's
// internal k-accumulation has limited alignment, so 2^-8-class split
// corrections co-resident with O(1) terms (y^2, x^2) are truncated =>
// effective bf16 precision => min-selection bias ~3-5e-2.  R5 passed
// because each of its k-trees was scale-homogeneous, scales joined via the
// exact-fp32 C chain.
//
// Fix: split d2 into two homogeneous trees joined by C:
//   HI (C=0):   xh0*h0 + xh1*h1 + xh2*h2 + x2h*1 + 1*qh        (all O(1))
//   LO (C=HI):  xh0*m0 + xm0*h0 + xh1*m1 + xm1*h1 + xh2*m2
//               + xm2*h2 + x2m*1 + 1*qm                        (all ~2^-8)
//   (h,m = 2-term bf16 split of -2y_d; xh,xm of x_d; x2*,q* of x^2,y^2;
//    dropped xm*m terms ~2^-18 => d2 error ~2e-5.)
// Both B vectors live in half-0's 8 slots (half-1 zero); A is scattered by
// the MEASURED A<->B slot bijection beta (R6 probe, guards retained).
// Epilogue: probe-keyed per-row atomicMin (verified R4/R5).
// Occupancy: RPB=128, grid 512 = 2 blocks/CU (R5 was grid-limited at 20%).
// B-fragments pre-built in LDS (2 x b128 read/tile on the hot path).
// ---------------------------------------------------------------------------

typedef __attribute__((ext_vector_type(8))) short bf16x8;   // 8 bf16 = 4 VGPR
typedef __attribute__((ext_vector_type(16))) float f32x16;  // 32x32 acc

static_assert(sizeof(bf16x8) == 16, "frag size");

__device__ inline unsigned short bf16_rne(float v) {
  unsigned u = __builtin_bit_cast(unsigned, v);
  return (unsigned short)((u + 0x7FFFu + ((u >> 16) & 1u)) >> 16);
}
__device__ inline float bf16_up(unsigned short u) {
  return __builtin_bit_cast(float, (unsigned)u << 16);
}

#define ONE_BF16 ((short)0x3F80)      // 1.0
#define SIXT_BF16 ((short)0x3D80)     // 0.0625

__device__ inline bf16x8 rep8(short s) {
  bf16x8 v;
  v[0] = s; v[1] = s; v[2] = s; v[3] = s;
  v[4] = s; v[5] = s; v[6] = s; v[7] = s;
  return v;
}

__global__ __launch_bounds__(TPB, 4) void chamfer_main(
    const float* __restrict__ pred, const float* __restrict__ label,
    float* __restrict__ blocksum) {
  // Fragment staging: per tile t (32 cols), col c: HI frag 16B at
  // t*1024 + (c&31)*16, LO frag at +512.  kg0 lanes b128-read them;
  // kg1 lanes supply the zero half.
  __shared__ __align__(1024) char stage[16 * 1024];
  __shared__ unsigned smin_u[RPB];  // per-row min of d2, uint-ordered
  __shared__ float ssum[8];

  const int tid = threadIdx.x;
  const int lane = tid & 63;
  const int w = tid >> 6;   // wave 0..7
  const int rg = w & 3;     // row group of 32 rows
  const int ch = w >> 2;    // which 8-tile half of each chunk
  const int kg = lane >> 5; // lane-half (physical operand half)
  const int b = blockIdx.y;
  const int dir = blockIdx.z;
  const int rowBase = blockIdx.x * RPB;

  const float* __restrict__ rows = dir ? label : pred;
  const float* __restrict__ cols = dir ? pred : label;

  if (tid < RPB) smin_u[tid] = 0x7F800000u;  // +inf

  const f32x16 zero = {};
  float diag = 0.0f;

  // ---- PROBE 1: A<->B k-slot bijection (16 one-hot MFMAs; R6, verified
  //      to pass guards on-chip).  beta[h*8+m] = A slot paired with B slot
  //      (h,m).  Guards: exact pow2, in-range, full 16-permutation.
  int beta[16];
  {
    bf16x8 pa;
#pragma unroll
    for (int e = 0; e < 8; ++e)
      pa[e] = (short)((unsigned short)((127 + e + 8 * kg) << 7));
    unsigned hit = 0;
#pragma unroll
    for (int h = 0; h < 2; ++h)
#pragma unroll
      for (int m = 0; m < 8; ++m) {
        bf16x8 pb = rep8(0);
        if (kg == h) pb[m] = ONE_BF16;
        const f32x16 pr =
            __builtin_amdgcn_mfma_f32_32x32x16_bf16(pa, pb, zero, 0, 0, 0);
        const unsigned bits = __float_as_uint(pr[0]);
        const int s = (int)((bits >> 23) & 0xFFu) - 127;
        beta[h * 8 + m] = s & 15;
        hit |= 1u << (s & 15);
        if ((bits & 0x7FFFFFu) != 0u || s < 0 || s > 15) diag += 1.0e9f;
      }
    if (hit != 0xFFFFu) diag += 1.0e9f;
  }

  // ---- PROBE 2: row labels for the epilogue (R4/R5, verified). ----
  int rowid[16];
  {
    const bf16x8 pa = rep8((short)bf16_rne((float)(lane & 31)));
    const bf16x8 pb = rep8(SIXT_BF16);
    const f32x16 pr =
        __builtin_amdgcn_mfma_f32_32x32x16_bf16(pa, pb, zero, 0, 0, 0);
#pragma unroll
    for (int i = 0; i < 16; ++i) {
      const float r = pr[i];
      const int ri = (int)(r + 0.5f);
      rowid[i] = ri & 31;
      if (fabsf(r - (float)ri) > 0.01f) diag += 1.0e9f;
    }
  }

  // ---- A fragments (one 32-row tile per wave), scattered by beta.
  //      Logical (B half-0 slot m):
  //        LB_HI = [h0, h1, h2, 1,  qh, 0, 0, 0]
  //        LA_HI = [xh0,xh1,xh2,x2h, 1, 0, 0, 0]
  //        LB_LO = [m0, h0, m1, h1, m2, h2, 1,  qm]
  //        LA_LO = [xh0,xm0,xh1,xm1,xh2,xm2,x2m, 1]
  bf16x8 aHI, aLO;
  {
    const int rrow = rowBase + rg * 32 + (lane & 31);
    const float* p = rows + ((size_t)b * NPTS + rrow) * 3;
    const float x0 = p[0], x1 = p[1], x2 = p[2];
    const unsigned short xh0 = bf16_rne(x0);
    const unsigned short xm0 = bf16_rne(x0 - bf16_up(xh0));
    const unsigned short xh1 = bf16_rne(x1);
    const unsigned short xm1 = bf16_rne(x1 - bf16_up(xh1));
    const unsigned short xh2 = bf16_rne(x2);
    const unsigned short xm2 = bf16_rne(x2 - bf16_up(xh2));
    const float xx = x0 * x0 + x1 * x1 + x2 * x2;
    const unsigned short x2h = bf16_rne(xx);
    const unsigned short x2m = bf16_rne(xx - bf16_up(x2h));
    const unsigned short LAHI[8] = {xh0, xh1, xh2, x2h,
                                    (unsigned short)0x3F80, 0, 0, 0};
    const unsigned short LALO[8] = {xh0, xm0, xh1, xm1, xh2, xm2, x2m,
                                    (unsigned short)0x3F80};
    unsigned short avH[8] = {0, 0, 0, 0, 0, 0, 0, 0};
    unsigned short avL[8] = {0, 0, 0, 0, 0, 0, 0, 0};
#pragma unroll
    for (int m = 0; m < 8; ++m) {
      const int s = beta[m];  // pairing of B half-0 slot m
      if ((s >> 3) == kg) {
        avH[s & 7] = LAHI[m];
        avL[s & 7] = LALO[m];
      }
    }
#pragma unroll
    for (int e = 0; e < 8; ++e) { aHI[e] = (short)avH[e]; aLO[e] = (short)avL[e]; }
  }

  float mn[16];
#pragma unroll
  for (int i = 0; i < 16; ++i) mn[i] = 3.0e38f;

  const bf16x8 bzero = rep8(0);

  for (int c = 0; c < NCHUNK; ++c) {
    __syncthreads();  // previous chunk fully consumed
    {
      // Build both B fragments for one column; write to LDS (b128 x2).
      const float* q = cols + ((size_t)b * NPTS + c * CHUNK_COLS + tid) * 3;
      const float y0 = q[0], y1 = q[1], y2 = q[2];
      const float a0 = -2.0f * y0, a1 = -2.0f * y1, a2 = -2.0f * y2;
      const unsigned short h0 = bf16_rne(a0);
      const unsigned short m0 = bf16_rne(a0 - bf16_up(h0));
      const unsigned short h1 = bf16_rne(a1);
      const unsigned short m1 = bf16_rne(a1 - bf16_up(h1));
      const unsigned short h2 = bf16_rne(a2);
      const unsigned short m2 = bf16_rne(a2 - bf16_up(h2));
      const float qq = y0 * y0 + y1 * y1 + y2 * y2;
      const unsigned short qh = bf16_rne(qq);
      const unsigned short qm = bf16_rne(qq - bf16_up(qh));
      bf16x8 gH, gL;
      gH[0] = (short)h0; gH[1] = (short)h1; gH[2] = (short)h2; gH[3] = ONE_BF16;
      gH[4] = (short)qh; gH[5] = 0;         gH[6] = 0;         gH[7] = 0;
      gL[0] = (short)m0; gL[1] = (short)h0; gL[2] = (short)m1; gL[3] = (short)h1;
      gL[4] = (short)m2; gL[5] = (short)h2; gL[6] = ONE_BF16;  gL[7] = (short)qm;
      char* bp = &stage[(tid >> 5) * 1024 + (tid & 31) * 16];
      *(bf16x8*)bp = gH;
      *(bf16x8*)(bp + 512) = gL;
    }
    __syncthreads();  // chunk staged

    // Wave's col-tiles: ch*8 .. ch*8+7, in pairs; 2 MFMAs per tile
    // (HI tree C=0, LO tree C-chained).  kg1 lanes supply zero B half.
#pragma unroll
    for (int p = 0; p < 8; p += 2) {
      const char* rd0 = &stage[(ch * 8 + p) * 1024 + (lane & 31) * 16];
      const bf16x8 bH0 = kg ? bzero : *(const bf16x8*)rd0;
      const bf16x8 bL0 = kg ? bzero : *(const bf16x8*)(rd0 + 512);
      const bf16x8 bH1 = kg ? bzero : *(const bf16x8*)(rd0 + 1024);
      const bf16x8 bL1 = kg ? bzero : *(const bf16x8*)(rd0 + 1536);
      f32x16 t0 = __builtin_amdgcn_mfma_f32_32x32x16_bf16(aHI, bH0, zero, 0, 0, 0);
      t0 = __builtin_amdgcn_mfma_f32_32x32x16_bf16(aLO, bL0, t0, 0, 0, 0);
      f32x16 t1 = __builtin_amdgcn_mfma_f32_32x32x16_bf16(aHI, bH1, zero, 0, 0, 0);
      t1 = __builtin_amdgcn_mfma_f32_32x32x16_bf16(aLO, bL1, t1, 0, 0, 0);
#pragma unroll
      for (int i = 0; i < 16; ++i)
        asm("v_min3_f32 %0, %0, %1, %2" : "+v"(mn[i]) : "v"(t0[i]), "v"(t1[i]));
    }
  }

  // ---- epilogue: probe-keyed per-row atomicMin (verified R4/R5) ----
#pragma unroll
  for (int i = 0; i < 16; ++i)
    atomicMin(&smin_u[rg * 32 + rowid[i]], __float_as_uint(mn[i]));
  __syncthreads();

  float v = diag;  // 0 healthy; >=1e9 if a probe guard fired
  if (tid < RPB) v += sqrtf(fmaxf(__uint_as_float(smin_u[tid]), 0.0f));
#pragma unroll
  for (int off = 32; off > 0; off >>= 1) v += __shfl_down(v, off, 64);
  if (lane == 0) ssum[w] = v;
  __syncthreads();
  if (tid == 0) {
    blocksum[((size_t)dir * BATCH + b) * NBLK + blockIdx.x] =
        ssum[0] + ssum[1] + ssum[2] + ssum[3] +
        ssum[4] + ssum[5] + ssum[6] + ssum[7];
  }
}

// One block sums the 512 per-block partials and OVERWRITES out[0]
// (deterministic, idempotent across graph replays).
__global__ __launch_bounds__(512) void chamfer_finish(
    const float* __restrict__ blocksum, float* __restrict__ out) {
  float v = blocksum[threadIdx.x];
#pragma unroll
  for (int off = 32; off > 0; off >>= 1) v += __shfl_down(v, off, 64);
  __shared__ float s8[8];
  const int wid = threadIdx.x >> 6;
  const int lane = threadIdx.x & 63;
  if (lane == 0) s8[wid] = v;
  __syncthreads();
  if (threadIdx.x == 0)
    out[0] = (s8[0] + s8[1] + s8[2] + s8[3] + s8[4] + s8[5] + s8[6] + s8[7]) *
             (1.0f / (float)(BATCH * NPTS));
}

extern "C" void kernel_launch(void* const* d_in, const int* in_sizes, int n_in,
                              void* d_out, int out_size, void* d_ws,
                              size_t ws_size, hipStream_t stream) {
  const float* pred = (const float*)d_in[0];
  const float* label = (const float*)d_in[1];
  float* out = (float*)d_out;
  float* blocksum = (float*)d_ws;  // 512 floats (ws >= 4 MB confirmed)

  chamfer_main<<<dim3(NBLK, BATCH, 2), TPB, 0, stream>>>(pred, label, blocksum);
  chamfer_finish<<<1, 512, 0, stream>>>(blocksum, out);
}